// Round 1
// baseline (1315.244 us; speedup 1.0000x reference)
//
#include <hip/hip_runtime.h>
#include <hip/hip_bf16.h>

typedef __attribute__((ext_vector_type(8))) short short8_t;
typedef __attribute__((ext_vector_type(4))) short short4_t;
typedef __attribute__((ext_vector_type(4))) float f32x4;

#define NTOK 37632
#define L1 2351

__device__ __forceinline__ unsigned short f2bf(float f) {
    union { float f; unsigned u; } v; v.f = f;
    unsigned r = (v.u + 0x7FFFu + ((v.u >> 16) & 1u)) >> 16;
    return (unsigned short)r;
}

// ---------------- prep kernels: reorder + bf16-cast weights ----------------
__global__ void prep_wc1(const float* __restrict__ w, unsigned short* __restrict__ out) {
    int k = blockIdx.x * 256 + threadIdx.x;   // 0..4095  (k = kt*128+ci)
    int co = blockIdx.y;                      // 0..255
    int kt = k >> 7, ci = k & 127;
    out[co * 4096 + k] = f2bf(w[co * 4096 + ci * 32 + kt]);
}
__global__ void prep_wc2(const float* __restrict__ w, unsigned short* __restrict__ out) {
    int k = blockIdx.x * 256 + threadIdx.x;   // 0..16127 (k = kt*256+ci)
    int co = blockIdx.y;                      // 0..511
    int kt = k >> 8, ci = k & 255;
    out[co * 16128 + k] = f2bf(w[co * 16128 + ci * 63 + kt]);
}
__global__ void prep_lin2(const float* __restrict__ w, unsigned short* __restrict__ out) {
    int idx = blockIdx.x * 256 + threadIdx.x;  // < 73728*160
    int j = idx / 160, k = idx - j * 160;
    out[idx] = (k < 144) ? f2bf(w[j * 144 + k]) : (unsigned short)0;
}
__global__ void prep_wt(const float* __restrict__ w, float* __restrict__ out) {
    int idx = blockIdx.x * 256 + threadIdx.x;  // < 46080 ; out[c][r][ci]
    int c = idx / 15360, rem = idx % 15360, r = rem / 512, ci = rem % 512;
    out[idx] = w[c * 15360 + ci * 30 + r];
}

// ---------------- conv1: emb-gather fused GEMM, M=256 N=2351 K=4096 ----------------
// emb table lives in LDS (64KB, XOR-swizzled rows); B-frag = ds_read_b128 at token row.
__global__ __launch_bounds__(256, 2)
void conv1_kernel(const int* __restrict__ xin, const float* __restrict__ embw,
                  const unsigned short* __restrict__ wc1, unsigned short* __restrict__ t1out) {
    __shared__ unsigned short embS[32768];
    int tid = threadIdx.x;
    for (int i = tid; i < 32768; i += 256) {
        int t = i >> 7, ci = i & 127;
        int dst = (t << 7) | ((((ci >> 3) ^ t) & 15) << 3) | (ci & 7);
        embS[dst] = f2bf(embw[i]);
    }
    __syncthreads();

    int b = blockIdx.z;
    int p0 = blockIdx.x * 128;
    int m0 = blockIdx.y * 128;
    int wid = tid >> 6, lane = tid & 63;
    int wm = wid >> 1, wn = wid & 1;
    int l16 = lane & 15, kg = lane >> 4;

    const int* xb = xin + b * NTOK;
    const unsigned short* abase = wc1 + (m0 + wm * 64 + l16) * 4096 + kg * 8;

    int pst[4], pcol[4];
#pragma unroll
    for (int nt = 0; nt < 4; nt++) {
        int p = p0 + wn * 64 + nt * 16 + l16;
        pst[nt] = p;
        pcol[nt] = p < L1 ? p : (L1 - 1);
    }
    f32x4 acc[4][4];
#pragma unroll
    for (int i = 0; i < 4; i++)
#pragma unroll
        for (int j = 0; j < 4; j++) acc[i][j] = (f32x4){0.f, 0.f, 0.f, 0.f};

    int tok[4];
    for (int ks = 0; ks < 4096; ks += 32) {
        if ((ks & 127) == 0) {
            int t = ks >> 7;
#pragma unroll
            for (int nt = 0; nt < 4; nt++) tok[nt] = xb[16 * pcol[nt] + t];
        }
        int ci8 = ((ks & 127) >> 3) + kg;   // (ci0>>3)
        short8_t afr[4], bfr[4];
#pragma unroll
        for (int mt = 0; mt < 4; mt++)
            afr[mt] = *(const short8_t*)(abase + mt * 16 * 4096 + ks);
#pragma unroll
        for (int nt = 0; nt < 4; nt++) {
            int sw = ((ci8 ^ tok[nt]) & 15) << 3;
            bfr[nt] = *(const short8_t*)&embS[(tok[nt] << 7) + sw];
        }
#pragma unroll
        for (int mt = 0; mt < 4; mt++)
#pragma unroll
            for (int nt = 0; nt < 4; nt++)
                acc[mt][nt] = __builtin_amdgcn_mfma_f32_16x16x32_bf16(afr[mt], bfr[nt], acc[mt][nt], 0, 0, 0);
    }

#pragma unroll
    for (int mt = 0; mt < 4; mt++) {
        int co = m0 + wm * 64 + mt * 16 + kg * 4;
#pragma unroll
        for (int nt = 0; nt < 4; nt++) {
            int p = pst[nt];
            if (p >= L1) continue;
            short4_t pk;
            pk.x = (short)f2bf(acc[mt][nt].x);
            pk.y = (short)f2bf(acc[mt][nt].y);
            pk.z = (short)f2bf(acc[mt][nt].z);
            pk.w = (short)f2bf(acc[mt][nt].w);
            *(short4_t*)&t1out[((size_t)b * L1 + p) * 256 + co] = pk;
        }
    }
}

// ---------------- conv2: GEMM M=512 N=144 K=16128, B = contiguous window of T1 ----------------
__global__ __launch_bounds__(256, 2)
void conv2_kernel(const unsigned short* __restrict__ t1, const unsigned short* __restrict__ wc2,
                  float* __restrict__ out0) {
    int tid = threadIdx.x;
    int b = blockIdx.z;
    int pb = blockIdx.x * 48;
    int m0 = blockIdx.y * 256;
    int wid = tid >> 6, lane = tid & 63;
    int l16 = lane & 15, kg = lane >> 4;
    const unsigned short* t1b = t1 + (size_t)b * (L1 * 256);
    const unsigned short* abase = wc2 + (size_t)(m0 + wid * 64 + l16) * 16128 + kg * 8;

    f32x4 acc[4][3];
#pragma unroll
    for (int i = 0; i < 4; i++)
#pragma unroll
        for (int j = 0; j < 3; j++) acc[i][j] = (f32x4){0.f, 0.f, 0.f, 0.f};

    for (int ks = 0; ks < 16128; ks += 32) {
        short8_t afr[4], bfr[3];
#pragma unroll
        for (int mt = 0; mt < 4; mt++)
            afr[mt] = *(const short8_t*)(abase + (size_t)mt * 16 * 16128 + ks);
#pragma unroll
        for (int nt = 0; nt < 3; nt++)
            bfr[nt] = *(const short8_t*)(t1b + (pb + nt * 16 + l16) * 4096 + ks + kg * 8);
#pragma unroll
        for (int mt = 0; mt < 4; mt++)
#pragma unroll
            for (int nt = 0; nt < 3; nt++)
                acc[mt][nt] = __builtin_amdgcn_mfma_f32_16x16x32_bf16(afr[mt], bfr[nt], acc[mt][nt], 0, 0, 0);
    }
#pragma unroll
    for (int mt = 0; mt < 4; mt++) {
        int co = m0 + wid * 64 + mt * 16 + kg * 4;
#pragma unroll
        for (int nt = 0; nt < 3; nt++) {
            int p = pb + nt * 16 + l16;   // < 144 always (3*48 exact)
            *(f32x4*)&out0[((size_t)b * 144 + p) * 512 + co] = acc[mt][nt];
        }
    }
}

// ---------------- topo conv + Prim MST + sort + lin1 (one block per batch) ----------------
__global__ __launch_bounds__(256)
void topo_kernel(const float* __restrict__ out0, const float* __restrict__ wt,
                 const float* __restrict__ bias, const float* __restrict__ lin1w,
                 unsigned short* __restrict__ t1bf) {
    __shared__ float red[240];
    __shared__ float ptsS[60];
    __shared__ float wsS[19];
    __shared__ float pdS[19];
    int tid = threadIdx.x;
    int b = blockIdx.x;
    if (tid < 240) {
        int pair = tid >> 2, part = tid & 3;
        int c = pair / 20, q = pair % 20;
        int ci0 = part * 128;
        float s = 0.f;
        for (int r = 0; r < 30; r++) {
            const float* t2p = out0 + ((size_t)b * 144 + 6 * q + r) * 512 + ci0;
            const float* wp = wt + (c * 30 + r) * 512 + ci0;
#pragma unroll 8
            for (int i = 0; i < 128; i += 4) {
                f32x4 a = *(const f32x4*)(t2p + i);
                f32x4 w = *(const f32x4*)(wp + i);
                s += a.x * w.x + a.y * w.y + a.z * w.z + a.w * w.w;
            }
        }
        red[tid] = s;
    }
    __syncthreads();
    if (tid < 60) {
        float s = red[tid * 4] + red[tid * 4 + 1] + red[tid * 4 + 2] + red[tid * 4 + 3];
        int c = tid / 20, q = tid % 20;
        ptsS[q * 3 + c] = s + bias[c];
    }
    __syncthreads();
    if (tid < 32) {
        int j = tid;
        float px = 0.f, py = 0.f, pz = 0.f;
        if (j < 20) { px = ptsS[j * 3]; py = ptsS[j * 3 + 1]; pz = ptsS[j * 3 + 2]; }
        float dx = px - ptsS[0], dy = py - ptsS[1], dz = pz - ptsS[2];
        float dist = sqrtf(dx * dx + dy * dy + dz * dz + 1e-12f);
        bool intree = (j == 0);
        for (int it = 0; it < 19; it++) {
            float dv = (j < 20 && !intree) ? dist : 1e30f;
            int di = j;
#pragma unroll
            for (int off = 16; off; off >>= 1) {
                float ov = __shfl_xor(dv, off, 32);
                int oi = __shfl_xor(di, off, 32);
                if (ov < dv || (ov == dv && oi < di)) { dv = ov; di = oi; }
            }
            if (j == 0) wsS[it] = dv;           // min value = reference's d[argmin]
            if (j == di) intree = true;
            float ex = px - ptsS[di * 3], ey = py - ptsS[di * 3 + 1], ez = pz - ptsS[di * 3 + 2];
            float nd = sqrtf(ex * ex + ey * ey + ez * ez + 1e-12f);
            dist = fminf(dist, nd);
        }
    }
    __syncthreads();
    if (tid < 19) {  // rank-sort 19 values (stable for ties)
        float v = wsS[tid];
        int rank = 0;
        for (int t = 0; t < 19; t++) {
            float u = wsS[t];
            rank += (u < v || (u == v && t < tid)) ? 1 : 0;
        }
        pdS[rank] = v;
    }
    __syncthreads();
    if (tid < 160) {
        float s = 0.f;
        if (tid < 144) {
#pragma unroll
            for (int i = 0; i < 19; i++) s += pdS[i] * lin1w[tid * 19 + i];
            s = fmaxf(s, 0.f);
        }
        t1bf[b * 160 + tid] = (tid < 144) ? f2bf(s) : (unsigned short)0;
    }
}

// ---------------- lin2: GEMM M=32(b) N=73728 K=160(padded), relu epilogue ----------------
__global__ __launch_bounds__(256)
void lin2_kernel(const unsigned short* __restrict__ t1bf, const unsigned short* __restrict__ l2b,
                 float* __restrict__ out1) {
    int tid = threadIdx.x;
    int wid = tid >> 6, lane = tid & 63;
    int l16 = lane & 15, kg = lane >> 4;
    int n0 = blockIdx.x * 256 + wid * 64;
    f32x4 acc[2][4];
#pragma unroll
    for (int i = 0; i < 2; i++)
#pragma unroll
        for (int j = 0; j < 4; j++) acc[i][j] = (f32x4){0.f, 0.f, 0.f, 0.f};

    for (int ks = 0; ks < 160; ks += 32) {
        short8_t afr[2], bfr[4];
#pragma unroll
        for (int mt = 0; mt < 2; mt++)
            afr[mt] = *(const short8_t*)(t1bf + (mt * 16 + l16) * 160 + ks + kg * 8);
#pragma unroll
        for (int nt = 0; nt < 4; nt++)
            bfr[nt] = *(const short8_t*)(l2b + (size_t)(n0 + nt * 16 + l16) * 160 + ks + kg * 8);
#pragma unroll
        for (int mt = 0; mt < 2; mt++)
#pragma unroll
            for (int nt = 0; nt < 4; nt++)
                acc[mt][nt] = __builtin_amdgcn_mfma_f32_16x16x32_bf16(afr[mt], bfr[nt], acc[mt][nt], 0, 0, 0);
    }
#pragma unroll
    for (int mt = 0; mt < 2; mt++)
#pragma unroll
        for (int nt = 0; nt < 4; nt++) {
            int jj = n0 + nt * 16 + l16;
#pragma unroll
            for (int i = 0; i < 4; i++) {
                int brow = mt * 16 + kg * 4 + i;
                out1[(size_t)brow * 73728 + jj] = fmaxf(acc[mt][nt][i], 0.f);
            }
        }
}

extern "C" void kernel_launch(void* const* d_in, const int* in_sizes, int n_in,
                              void* d_out, int out_size, void* d_ws, size_t ws_size,
                              hipStream_t stream) {
    const int* x = (const int*)d_in[0];
    const float* embw = (const float*)d_in[1];
    const float* c1w = (const float*)d_in[2];
    const float* c2w = (const float*)d_in[3];
    const float* tw = (const float*)d_in[4];
    const float* tb = (const float*)d_in[5];
    const float* l1w = (const float*)d_in[6];
    const float* l2w = (const float*)d_in[7];
    float* out0 = (float*)d_out;                       // x_seq [32][144][512]
    float* out1 = out0 + (size_t)32 * 144 * 512;       // topo_all_fea

    char* ws = (char*)d_ws;
    unsigned short* wc1  = (unsigned short*)(ws);                  //  2,097,152 B
    unsigned short* wc2  = (unsigned short*)(ws + 2097152);        // 16,515,072 B
    unsigned short* t1   = (unsigned short*)(ws + 18612224);       // 38,518,784 B
    unsigned short* l2b  = (unsigned short*)(ws + 57131008);       // 23,592,960 B
    float*          wt   = (float*)(ws + 80723968);                //    184,320 B
    unsigned short* t1bf = (unsigned short*)(ws + 80908288);       //     10,240 B

    prep_wc1<<<dim3(16, 256), 256, 0, stream>>>(c1w, wc1);
    prep_wc2<<<dim3(63, 512), 256, 0, stream>>>(c2w, wc2);
    prep_lin2<<<dim3(46080), 256, 0, stream>>>(l2w, l2b);
    prep_wt<<<dim3(180), 256, 0, stream>>>(tw, wt);
    conv1_kernel<<<dim3(19, 2, 32), 256, 0, stream>>>(x, embw, wc1, t1);
    conv2_kernel<<<dim3(3, 2, 32), 256, 0, stream>>>(t1, wc2, out0);
    topo_kernel<<<dim3(32), 256, 0, stream>>>(out0, wt, tb, l1w, t1bf);
    lin2_kernel<<<dim3(288), 256, 0, stream>>>(t1bf, l2b, out1);
}

// Round 3
// 747.789 us; speedup vs baseline: 1.7588x; 1.7588x over previous
//
#include <hip/hip_runtime.h>
#include <hip/hip_bf16.h>

typedef __attribute__((ext_vector_type(8))) short short8_t;
typedef __attribute__((ext_vector_type(4))) short short4_t;
typedef __attribute__((ext_vector_type(4))) float f32x4;
typedef unsigned int u32;

#define NTOK 37632
#define L1 2351

__device__ __forceinline__ unsigned short f2bf(float f) {
    union { float f; unsigned u; } v; v.f = f;
    return (unsigned short)((v.u + 0x7FFFu + ((v.u >> 16) & 1u)) >> 16);
}

__device__ __forceinline__ void gload16(void* lds, const void* g) {
    __builtin_amdgcn_global_load_lds((const __attribute__((address_space(1))) u32*)g,
                                     (__attribute__((address_space(3))) u32*)lds, 16, 0, 0);
}

// ---------------- prep kernels: reorder + bf16-cast weights ----------------
__global__ void prep_wc1(const float* __restrict__ w, unsigned short* __restrict__ out) {
    int k = blockIdx.x * 256 + threadIdx.x;   // k = kt*128+ci
    int co = blockIdx.y;
    int kt = k >> 7, ci = k & 127;
    out[co * 4096 + k] = f2bf(w[co * 4096 + ci * 32 + kt]);
}
__global__ void prep_wc2(const float* __restrict__ w, unsigned short* __restrict__ out) {
    int k = blockIdx.x * 256 + threadIdx.x;   // k = kt*256+ci
    int co = blockIdx.y;
    int kt = k >> 8, ci = k & 255;
    out[co * 16128 + k] = f2bf(w[co * 16128 + ci * 63 + kt]);
}
__global__ void prep_wt(const float* __restrict__ w, float* __restrict__ out) {
    int idx = blockIdx.x * 256 + threadIdx.x;  // out[c][r][ci]
    int c = idx / 15360, rem = idx % 15360, r = rem / 512, ci = rem % 512;
    out[idx] = w[c * 15360 + ci * 30 + r];
}
__global__ void zero_out0(float* __restrict__ p) {
    int i = blockIdx.x * 256 + threadIdx.x;
    *(f32x4*)(p + i * 4) = (f32x4){0.f, 0.f, 0.f, 0.f};
}

// ---------------- conv1: emb-gather fused GEMM, M=256 N=2351 K=4096 ----------------
// Block: M=128 (m0), N=256; 4 waves, wave-tile 128x64 (8mt x 4nt).
// A staged via global_load_lds (dbuf 2x8KB, XOR-swizzled via pre-swizzled src);
// B gathered from 64KB LDS emb table (token-XOR-swizzled rows).
__global__ __launch_bounds__(256, 2)
void conv1_kernel(const int* __restrict__ xin, const float* __restrict__ embw,
                  const unsigned short* __restrict__ wc1, unsigned short* __restrict__ t1out) {
    __shared__ unsigned short embS[32768];      // 64 KB
    __shared__ unsigned short A_lds[2][4096];   // 2 x 8 KB (128 rows x 32 k)
    const int tid = threadIdx.x;

    // emb table -> LDS bf16, per-row slot XOR-swizzle by token
#pragma unroll
    for (int c = 0; c < 16; c++) {
        int e0 = c * 2048 + tid * 8;
        int tok = e0 >> 7;
        int slot = (tid & 15) ^ (tok & 15);
        f32x4 f0 = *(const f32x4*)(embw + e0);
        f32x4 f1 = *(const f32x4*)(embw + e0 + 4);
        short8_t v;
        v[0] = (short)f2bf(f0.x); v[1] = (short)f2bf(f0.y);
        v[2] = (short)f2bf(f0.z); v[3] = (short)f2bf(f0.w);
        v[4] = (short)f2bf(f1.x); v[5] = (short)f2bf(f1.y);
        v[6] = (short)f2bf(f1.z); v[7] = (short)f2bf(f1.w);
        *(short8_t*)&embS[tok * 128 + slot * 8] = v;
    }

    const int b = blockIdx.z;
    const int m0 = blockIdx.y;            // co base = m0*128
    const int p0 = blockIdx.x * 256;
    const int wid = tid >> 6, lane = tid & 63;
    const int l16 = lane & 15, kg = lane >> 4;
    const int* xb = xin + b * NTOK;

    int pst[4], pcol[4];
#pragma unroll
    for (int nt = 0; nt < 4; nt++) {
        int p = p0 + wid * 64 + nt * 16 + l16;
        pst[nt] = p; pcol[nt] = (p < L1) ? p : (L1 - 1);
    }

    // staging: thread t handles phys 16B chunks; inverse-swizzled global src
    const int srow0 = tid >> 2;
    const int srow1 = 64 + srow0;
    const unsigned short* asrc0 = wc1 + (m0 * 128 + srow0) * 4096 + (((tid & 3) ^ ((srow0 >> 1) & 3)) << 3);
    const unsigned short* asrc1 = wc1 + (m0 * 128 + srow1) * 4096 + (((tid & 3) ^ ((srow1 >> 1) & 3)) << 3);

    int aidx[8];
#pragma unroll
    for (int mt = 0; mt < 8; mt++) {
        int row = mt * 16 + l16;
        aidx[mt] = row * 32 + ((kg ^ ((row >> 1) & 3)) << 3);
    }

    f32x4 acc[8][4];
#pragma unroll
    for (int i = 0; i < 8; i++)
#pragma unroll
        for (int j = 0; j < 4; j++) acc[i][j] = (f32x4){0.f, 0.f, 0.f, 0.f};

    int tokn[4];
#pragma unroll
    for (int nt = 0; nt < 4; nt++) tokn[nt] = xb[16 * pcol[nt]];

    // prologue stage ks=0 into buf0
    {
        unsigned short* base = &A_lds[0][wid << 9];
        gload16(base, asrc0);
        gload16(base + 2048, asrc1);
    }
    __syncthreads();   // embS + buf0 ready

    int tokbase[4], tokxor[4];
    for (int ks = 0; ks < 4096; ks += 32) {
        int it = ks >> 5;
        if (it + 1 < 128) {
            unsigned short* base = &A_lds[(it + 1) & 1][wid << 9];
            gload16(base, asrc0 + ks + 32);
            gload16(base + 2048, asrc1 + ks + 32);
        }
        if ((ks & 127) == 0) {
#pragma unroll
            for (int nt = 0; nt < 4; nt++) { int tk = tokn[nt]; tokbase[nt] = tk << 7; tokxor[nt] = tk & 15; }
            int tnext = (ks >> 7) + 1;
            if (tnext < 32) {
#pragma unroll
                for (int nt = 0; nt < 4; nt++) tokn[nt] = xb[16 * pcol[nt] + tnext];
            }
        }
        const unsigned short* Ab = A_lds[it & 1];
        int s0 = (ks >> 3) & 15;
        short8_t bfr[4], afr[8];
#pragma unroll
        for (int nt = 0; nt < 4; nt++)
            bfr[nt] = *(const short8_t*)&embS[tokbase[nt] + (((s0 + kg) ^ tokxor[nt]) << 3)];
#pragma unroll
        for (int mt = 0; mt < 8; mt++)
            afr[mt] = *(const short8_t*)&Ab[aidx[mt]];
#pragma unroll
        for (int mt = 0; mt < 8; mt++)
#pragma unroll
            for (int nt = 0; nt < 4; nt++)
                acc[mt][nt] = __builtin_amdgcn_mfma_f32_16x16x32_bf16(afr[mt], bfr[nt], acc[mt][nt], 0, 0, 0);
        __syncthreads();   // drains next stage (vmcnt) + protects cur buf
    }

#pragma unroll
    for (int mt = 0; mt < 8; mt++) {
        int co = m0 * 128 + mt * 16 + kg * 4;
#pragma unroll
        for (int nt = 0; nt < 4; nt++) {
            int p = pst[nt];
            if (p >= L1) continue;
            short4_t pk;
            pk.x = (short)f2bf(acc[mt][nt].x);
            pk.y = (short)f2bf(acc[mt][nt].y);
            pk.z = (short)f2bf(acc[mt][nt].z);
            pk.w = (short)f2bf(acc[mt][nt].w);
            *(short4_t*)&t1out[((size_t)b * L1 + p) * 256 + co] = pk;
        }
    }
}

// ---------------- conv2: GEMM M=512 N=144 K=16128, K-split x4, atomic f32 epilogue ----------------
__global__ __launch_bounds__(256, 3)
void conv2_kernel(const unsigned short* __restrict__ t1, const unsigned short* __restrict__ wc2,
                  float* __restrict__ out0) {
    __shared__ unsigned short A_lds[2][8192];   // 2 x 16 KB (256 rows x 32 k)
    const int tid = threadIdx.x;
    const int pb = blockIdx.x * 48;
    const int m0 = blockIdx.y;                  // co base = m0*256
    const int b = blockIdx.z >> 2, kc = blockIdx.z & 3;
    const int k0 = kc * 4032;
    const int wid = tid >> 6, lane = tid & 63, l16 = lane & 15, kg = lane >> 4;
    const unsigned short* t1b = t1 + (size_t)b * (L1 * 256);

    const int srow = tid >> 2, sx = tid & 3;
    const unsigned short* asrc[4];
#pragma unroll
    for (int i = 0; i < 4; i++) {
        int row = i * 64 + srow;
        asrc[i] = wc2 + (size_t)(m0 * 256 + row) * 16128 + k0 + ((sx ^ ((row >> 1) & 3)) << 3);
    }
    int aidx[4];
#pragma unroll
    for (int mt = 0; mt < 4; mt++) {
        int row = wid * 64 + mt * 16 + l16;
        aidx[mt] = row * 32 + ((kg ^ ((row >> 1) & 3)) << 3);
    }
    const unsigned short* bbase[3];
#pragma unroll
    for (int nt = 0; nt < 3; nt++)
        bbase[nt] = t1b + (size_t)(pb + nt * 16 + l16) * 4096 + k0 + kg * 8;

    f32x4 acc[4][3];
#pragma unroll
    for (int i = 0; i < 4; i++)
#pragma unroll
        for (int j = 0; j < 3; j++) acc[i][j] = (f32x4){0.f, 0.f, 0.f, 0.f};

    {
        unsigned short* base = &A_lds[0][wid << 9];
#pragma unroll
        for (int i = 0; i < 4; i++) gload16(base + i * 2048, asrc[i]);
    }
    __syncthreads();

    for (int it = 0; it < 126; it++) {
        if (it + 1 < 126) {
            unsigned short* base = &A_lds[(it + 1) & 1][wid << 9];
#pragma unroll
            for (int i = 0; i < 4; i++) gload16(base + i * 2048, asrc[i] + (it + 1) * 32);
        }
        const unsigned short* Ab = A_lds[it & 1];
        int ks = it * 32;
        short8_t afr[4], bfr[3];
#pragma unroll
        for (int nt = 0; nt < 3; nt++) bfr[nt] = *(const short8_t*)(bbase[nt] + ks);
#pragma unroll
        for (int mt = 0; mt < 4; mt++) afr[mt] = *(const short8_t*)&Ab[aidx[mt]];
#pragma unroll
        for (int mt = 0; mt < 4; mt++)
#pragma unroll
            for (int nt = 0; nt < 3; nt++)
                acc[mt][nt] = __builtin_amdgcn_mfma_f32_16x16x32_bf16(afr[mt], bfr[nt], acc[mt][nt], 0, 0, 0);
        __syncthreads();
    }

#pragma unroll
    for (int mt = 0; mt < 4; mt++) {
        int co = m0 * 256 + wid * 64 + mt * 16 + kg * 4;
#pragma unroll
        for (int nt = 0; nt < 3; nt++) {
            int p = pb + nt * 16 + l16;
            float* dst = out0 + ((size_t)b * 144 + p) * 512 + co;
            atomicAdd(dst + 0, acc[mt][nt].x);
            atomicAdd(dst + 1, acc[mt][nt].y);
            atomicAdd(dst + 2, acc[mt][nt].z);
            atomicAdd(dst + 3, acc[mt][nt].w);
        }
    }
}

// ---------------- topo: wave-per-(c,q) dot, then per-batch MST+sort+lin1 ----------------
__global__ __launch_bounds__(64)
void topo_pts(const float* __restrict__ out0, const float* __restrict__ wt,
              float* __restrict__ pts) {
    int lane = threadIdx.x;
    int cq = blockIdx.x;                 // 0..59
    int b = blockIdx.y;
    int c = cq / 20, q = cq % 20;
    const float* xbase = out0 + ((size_t)b * 144 + 6 * q) * 512 + lane * 8;
    const float* wbase = wt + c * 15360 + lane * 8;
    float s = 0.f;
    for (int r = 0; r < 30; r++) {
        f32x4 a0 = *(const f32x4*)(xbase + r * 512);
        f32x4 a1 = *(const f32x4*)(xbase + r * 512 + 4);
        f32x4 w0 = *(const f32x4*)(wbase + r * 512);
        f32x4 w1 = *(const f32x4*)(wbase + r * 512 + 4);
        s += a0.x * w0.x + a0.y * w0.y + a0.z * w0.z + a0.w * w0.w
           + a1.x * w1.x + a1.y * w1.y + a1.z * w1.z + a1.w * w1.w;
    }
#pragma unroll
    for (int off = 32; off; off >>= 1) s += __shfl_xor(s, off);
    if (lane == 0) pts[b * 60 + q * 3 + c] = s;
}

__global__ __launch_bounds__(192)
void topo_fin(const float* __restrict__ pts, const float* __restrict__ bias,
              const float* __restrict__ lin1w, unsigned short* __restrict__ t1bf) {
    __shared__ float ptsS[60];
    __shared__ float wsS[19];
    __shared__ float pdS[19];
    int tid = threadIdx.x, b = blockIdx.x;
    if (tid < 60) ptsS[tid] = pts[b * 60 + tid] + bias[tid % 3];
    __syncthreads();
    if (tid < 32) {
        int j = tid;
        float px = 0.f, py = 0.f, pz = 0.f;
        if (j < 20) { px = ptsS[j * 3]; py = ptsS[j * 3 + 1]; pz = ptsS[j * 3 + 2]; }
        float dx = px - ptsS[0], dy = py - ptsS[1], dz = pz - ptsS[2];
        float dist = sqrtf(dx * dx + dy * dy + dz * dz + 1e-12f);
        bool intree = (j == 0);
        for (int it = 0; it < 19; it++) {
            float dv = (j < 20 && !intree) ? dist : 1e30f;
            int di = j;
#pragma unroll
            for (int off = 16; off; off >>= 1) {
                float ov = __shfl_xor(dv, off, 32);
                int oi = __shfl_xor(di, off, 32);
                if (ov < dv || (ov == dv && oi < di)) { dv = ov; di = oi; }
            }
            if (j == 0) wsS[it] = dv;
            if (j == di) intree = true;
            float ex = px - ptsS[di * 3], ey = py - ptsS[di * 3 + 1], ez = pz - ptsS[di * 3 + 2];
            float nd = sqrtf(ex * ex + ey * ey + ez * ez + 1e-12f);
            dist = fminf(dist, nd);
        }
    }
    __syncthreads();
    if (tid < 19) {
        float v = wsS[tid];
        int rank = 0;
        for (int t = 0; t < 19; t++) {
            float u = wsS[t];
            rank += (u < v || (u == v && t < tid)) ? 1 : 0;
        }
        pdS[rank] = v;
    }
    __syncthreads();
    if (tid < 160) {
        float s = 0.f;
        if (tid < 144) {
#pragma unroll
            for (int i = 0; i < 19; i++) s += pdS[i] * lin1w[tid * 19 + i];
            s = fmaxf(s, 0.f);
        }
        t1bf[b * 160 + tid] = (tid < 144) ? f2bf(s) : (unsigned short)0;
    }
}

// ---------------- lin2: GEMM M=32 N=73728 K=144(pad 160), f32 weights, relu ----------------
__global__ __launch_bounds__(256)
void lin2_kernel(const unsigned short* __restrict__ t1bf, const float* __restrict__ l2w,
                 float* __restrict__ out1) {
    const int tid = threadIdx.x;
    const int wid = tid >> 6, lane = tid & 63, l16 = lane & 15, kg = lane >> 4;
    const int n0 = blockIdx.x * 256 + wid * 64;
    f32x4 acc[2][4];
#pragma unroll
    for (int i = 0; i < 2; i++)
#pragma unroll
        for (int j = 0; j < 4; j++) acc[i][j] = (f32x4){0.f, 0.f, 0.f, 0.f};

#pragma unroll
    for (int ki = 0; ki < 5; ki++) {
        int kbase = ki * 32 + kg * 8;
        short8_t afr[2], bfr[4];
#pragma unroll
        for (int mt = 0; mt < 2; mt++)
            afr[mt] = *(const short8_t*)(t1bf + (mt * 16 + l16) * 160 + kbase);
#pragma unroll
        for (int nt = 0; nt < 4; nt++) {
            int j = n0 + nt * 16 + l16;
            short8_t v;
            if (kbase < 144) {
                const float* wp = l2w + j * 144 + kbase;
                f32x4 f0 = *(const f32x4*)wp;
                f32x4 f1 = *(const f32x4*)(wp + 4);
                v[0] = (short)f2bf(f0.x); v[1] = (short)f2bf(f0.y);
                v[2] = (short)f2bf(f0.z); v[3] = (short)f2bf(f0.w);
                v[4] = (short)f2bf(f1.x); v[5] = (short)f2bf(f1.y);
                v[6] = (short)f2bf(f1.z); v[7] = (short)f2bf(f1.w);
            } else {
#pragma unroll
                for (int i = 0; i < 8; i++) v[i] = 0;
            }
            bfr[nt] = v;
        }
#pragma unroll
        for (int mt = 0; mt < 2; mt++)
#pragma unroll
            for (int nt = 0; nt < 4; nt++)
                acc[mt][nt] = __builtin_amdgcn_mfma_f32_16x16x32_bf16(afr[mt], bfr[nt], acc[mt][nt], 0, 0, 0);
    }
#pragma unroll
    for (int mt = 0; mt < 2; mt++)
#pragma unroll
        for (int nt = 0; nt < 4; nt++) {
            int jj = n0 + nt * 16 + l16;
#pragma unroll
            for (int i = 0; i < 4; i++) {
                int brow = mt * 16 + kg * 4 + i;
                out1[(size_t)brow * 73728 + jj] = fmaxf(acc[mt][nt][i], 0.f);
            }
        }
}

extern "C" void kernel_launch(void* const* d_in, const int* in_sizes, int n_in,
                              void* d_out, int out_size, void* d_ws, size_t ws_size,
                              hipStream_t stream) {
    const int* x = (const int*)d_in[0];
    const float* embw = (const float*)d_in[1];
    const float* c1w = (const float*)d_in[2];
    const float* c2w = (const float*)d_in[3];
    const float* tw = (const float*)d_in[4];
    const float* tb = (const float*)d_in[5];
    const float* l1w = (const float*)d_in[6];
    const float* l2w = (const float*)d_in[7];
    float* out0 = (float*)d_out;                       // x_seq [32][144][512]
    float* out1 = out0 + (size_t)32 * 144 * 512;       // topo_all_fea

    char* ws = (char*)d_ws;
    unsigned short* wc1  = (unsigned short*)(ws);                  //  2,097,152 B
    unsigned short* wc2  = (unsigned short*)(ws + 2097152);        // 16,515,072 B
    unsigned short* t1   = (unsigned short*)(ws + 18612224);       // 38,518,784 B
    float*          wt   = (float*)(ws + 57131008);                //    184,320 B
    float*          pts  = (float*)(ws + 57315328);                //      7,680 B
    unsigned short* t1bf = (unsigned short*)(ws + 57323008);       //     10,240 B

    zero_out0<<<dim3(2304), 256, 0, stream>>>(out0);
    prep_wc1<<<dim3(16, 256), 256, 0, stream>>>(c1w, wc1);
    prep_wc2<<<dim3(63, 512), 256, 0, stream>>>(c2w, wc2);
    prep_wt<<<dim3(180), 256, 0, stream>>>(tw, wt);
    conv1_kernel<<<dim3(10, 2, 32), 256, 0, stream>>>(x, embw, wc1, t1);
    conv2_kernel<<<dim3(3, 2, 128), 256, 0, stream>>>(t1, wc2, out0);
    topo_pts<<<dim3(60, 32), 64, 0, stream>>>(out0, wt, pts);
    topo_fin<<<dim3(32), 192, 0, stream>>>(pts, tb, l1w, t1bf);
    lin2_kernel<<<dim3(288), 256, 0, stream>>>(t1bf, l2w, out1);
}

// Round 6
// 701.036 us; speedup vs baseline: 1.8761x; 1.0667x over previous
//
#include <hip/hip_runtime.h>
#include <hip/hip_bf16.h>

typedef __attribute__((ext_vector_type(8))) short short8_t;
typedef __attribute__((ext_vector_type(4))) short short4_t;
typedef __attribute__((ext_vector_type(4))) float f32x4;
typedef unsigned int u32;

#define NTOK 37632
#define L1 2351

__device__ __forceinline__ unsigned short f2bf(float f) {
    union { float f; unsigned u; } v; v.f = f;
    return (unsigned short)((v.u + 0x7FFFu + ((v.u >> 16) & 1u)) >> 16);
}

__device__ __forceinline__ void gload16(void* lds, const void* g) {
    __builtin_amdgcn_global_load_lds((const __attribute__((address_space(1))) u32*)g,
                                     (__attribute__((address_space(3))) u32*)lds, 16, 0, 0);
}

// ---------------- prep kernels: reorder + bf16-cast weights ----------------
__global__ void prep_wc1(const float* __restrict__ w, unsigned short* __restrict__ out) {
    int k = blockIdx.x * 256 + threadIdx.x;   // k = kt*128+ci
    int co = blockIdx.y;
    int kt = k >> 7, ci = k & 127;
    out[co * 4096 + k] = f2bf(w[co * 4096 + ci * 32 + kt]);
}
__global__ void prep_wc2(const float* __restrict__ w, unsigned short* __restrict__ out) {
    int k = blockIdx.x * 256 + threadIdx.x;   // k = kt*256+ci
    int co = blockIdx.y;
    int kt = k >> 8, ci = k & 255;
    out[co * 16128 + k] = f2bf(w[co * 16128 + ci * 63 + kt]);
}
__global__ void prep_wt(const float* __restrict__ w, float* __restrict__ out) {
    int idx = blockIdx.x * 256 + threadIdx.x;  // out[c][r][ci]
    int c = idx / 15360, rem = idx % 15360, r = rem / 512, ci = rem % 512;
    out[idx] = w[c * 15360 + ci * 30 + r];
}

// ---------------- conv1: emb-gather fused GEMM, M=256 N=2351 K=4096 ----------------
__global__ __launch_bounds__(256, 2)
void conv1_kernel(const int* __restrict__ xin, const float* __restrict__ embw,
                  const unsigned short* __restrict__ wc1, unsigned short* __restrict__ t1out) {
    __shared__ unsigned short embS[32768];      // 64 KB
    __shared__ unsigned short A_lds[2][4096];   // 2 x 8 KB (128 rows x 32 k)
    const int tid = threadIdx.x;

#pragma unroll
    for (int c = 0; c < 16; c++) {
        int e0 = c * 2048 + tid * 8;
        int tok = e0 >> 7;
        int slot = (tid & 15) ^ (tok & 15);
        f32x4 f0 = *(const f32x4*)(embw + e0);
        f32x4 f1 = *(const f32x4*)(embw + e0 + 4);
        short8_t v;
        v[0] = (short)f2bf(f0.x); v[1] = (short)f2bf(f0.y);
        v[2] = (short)f2bf(f0.z); v[3] = (short)f2bf(f0.w);
        v[4] = (short)f2bf(f1.x); v[5] = (short)f2bf(f1.y);
        v[6] = (short)f2bf(f1.z); v[7] = (short)f2bf(f1.w);
        *(short8_t*)&embS[tok * 128 + slot * 8] = v;
    }

    const int b = blockIdx.z;
    const int m0 = blockIdx.y;            // co base = m0*128
    const int p0 = blockIdx.x * 256;
    const int wid = tid >> 6, lane = tid & 63;
    const int l16 = lane & 15, kg = lane >> 4;
    const int* xb = xin + b * NTOK;

    int pst[4], pcol[4];
#pragma unroll
    for (int nt = 0; nt < 4; nt++) {
        int p = p0 + wid * 64 + nt * 16 + l16;
        pst[nt] = p; pcol[nt] = (p < L1) ? p : (L1 - 1);
    }

    const int srow0 = tid >> 2;
    const int srow1 = 64 + srow0;
    const unsigned short* asrc0 = wc1 + (m0 * 128 + srow0) * 4096 + (((tid & 3) ^ ((srow0 >> 1) & 3)) << 3);
    const unsigned short* asrc1 = wc1 + (m0 * 128 + srow1) * 4096 + (((tid & 3) ^ ((srow1 >> 1) & 3)) << 3);

    int aidx[8];
#pragma unroll
    for (int mt = 0; mt < 8; mt++) {
        int row = mt * 16 + l16;
        aidx[mt] = row * 32 + ((kg ^ ((row >> 1) & 3)) << 3);
    }

    f32x4 acc[8][4];
#pragma unroll
    for (int i = 0; i < 8; i++)
#pragma unroll
        for (int j = 0; j < 4; j++) acc[i][j] = (f32x4){0.f, 0.f, 0.f, 0.f};

    int tokn[4];
#pragma unroll
    for (int nt = 0; nt < 4; nt++) tokn[nt] = xb[16 * pcol[nt]];

    {
        unsigned short* base = &A_lds[0][wid << 9];
        gload16(base, asrc0);
        gload16(base + 2048, asrc1);
    }
    __syncthreads();

    int tokbase[4], tokxor[4];
    for (int ks = 0; ks < 4096; ks += 32) {
        int it = ks >> 5;
        if (it + 1 < 128) {
            unsigned short* base = &A_lds[(it + 1) & 1][wid << 9];
            gload16(base, asrc0 + ks + 32);
            gload16(base + 2048, asrc1 + ks + 32);
        }
        if ((ks & 127) == 0) {
#pragma unroll
            for (int nt = 0; nt < 4; nt++) { int tk = tokn[nt]; tokbase[nt] = tk << 7; tokxor[nt] = tk & 15; }
            int tnext = (ks >> 7) + 1;
            if (tnext < 32) {
#pragma unroll
                for (int nt = 0; nt < 4; nt++) tokn[nt] = xb[16 * pcol[nt] + tnext];
            }
        }
        const unsigned short* Ab = A_lds[it & 1];
        int s0 = (ks >> 3) & 15;
        short8_t bfr[4], afr[8];
#pragma unroll
        for (int nt = 0; nt < 4; nt++)
            bfr[nt] = *(const short8_t*)&embS[tokbase[nt] + (((s0 + kg) ^ tokxor[nt]) << 3)];
#pragma unroll
        for (int mt = 0; mt < 8; mt++)
            afr[mt] = *(const short8_t*)&Ab[aidx[mt]];
#pragma unroll
        for (int mt = 0; mt < 8; mt++)
#pragma unroll
            for (int nt = 0; nt < 4; nt++)
                acc[mt][nt] = __builtin_amdgcn_mfma_f32_16x16x32_bf16(afr[mt], bfr[nt], acc[mt][nt], 0, 0, 0);
        __syncthreads();
    }

#pragma unroll
    for (int mt = 0; mt < 8; mt++) {
        int co = m0 * 128 + mt * 16 + kg * 4;
#pragma unroll
        for (int nt = 0; nt < 4; nt++) {
            int p = pst[nt];
            if (p >= L1) continue;
            short4_t pk;
            pk.x = (short)f2bf(acc[mt][nt].x);
            pk.y = (short)f2bf(acc[mt][nt].y);
            pk.z = (short)f2bf(acc[mt][nt].z);
            pk.w = (short)f2bf(acc[mt][nt].w);
            *(short4_t*)&t1out[((size_t)b * L1 + p) * 256 + co] = pk;
        }
    }
}

// ---------------- conv2: GEMM M=512 N=32x144 K=16128 ----------------
// Block: BM=128 x BN=144 (one batch), BK=64, K-split x4 via partial buffers.
// XCD-pinned: combo=(m0,kc)=bid&15 -> XCD combo%8; A-slice (1MB) stays L2-resident.
__global__ __launch_bounds__(256, 2)
void conv2_kernel(const unsigned short* __restrict__ t1, const unsigned short* __restrict__ wc2,
                  float* __restrict__ out0, float* __restrict__ parts) {
    __shared__ unsigned short A_lds[2][8192];   // 2 x 16 KB: [128 rows][64 k], chunk-XOR swizzled
    const int tid = threadIdx.x;
    const int bid = blockIdx.x;
    const int combo = bid & 15, batch = bid >> 4;
    const int m0 = combo & 3, kc = combo >> 2;
    const int k0 = kc * 4032;
    const int wid = tid >> 6, lane = tid & 63, l16 = lane & 15, kg = lane >> 4;
    const unsigned short* t1b = t1 + (size_t)batch * (L1 * 256);

    // staging: thread handles 4 chunks (rows i*32 + tid>>3, chunk tid&7), inverse-swizzled src
    const int srow = tid >> 3, schunk = tid & 7;
    const unsigned short* asrc[4];
#pragma unroll
    for (int i = 0; i < 4; i++) {
        int r = i * 32 + srow;
        asrc[i] = wc2 + (size_t)(m0 * 128 + r) * 16128 + k0 + ((schunk ^ (r & 7)) << 3);
    }

    // ds_read indices: row = wid*32 + mt*16 + l16; logical chunk = kg + ks*4; phys ^= row&7
    int arow[2];
#pragma unroll
    for (int mt = 0; mt < 2; mt++) arow[mt] = (wid * 32 + mt * 16 + l16) * 64;
    const int axor = l16 & 7;

    const unsigned short* bbase[9];
#pragma unroll
    for (int nt = 0; nt < 9; nt++)
        bbase[nt] = t1b + (size_t)(nt * 16 + l16) * 4096 + k0 + kg * 8;

    f32x4 acc[2][9];
#pragma unroll
    for (int i = 0; i < 2; i++)
#pragma unroll
        for (int j = 0; j < 9; j++) acc[i][j] = (f32x4){0.f, 0.f, 0.f, 0.f};

    {   // prologue: stage it=0 into buf0  (wave base = wid*1024 B = wid<<9 shorts)
        unsigned short* base = &A_lds[0][wid << 9];
#pragma unroll
        for (int i = 0; i < 4; i++) gload16(base + i * 2048, asrc[i]);
    }
    __syncthreads();

    for (int it = 0; it < 63; it++) {
        if (it + 1 < 63) {
            unsigned short* base = &A_lds[(it + 1) & 1][wid << 9];
#pragma unroll
            for (int i = 0; i < 4; i++) gload16(base + i * 2048, asrc[i] + (it + 1) * 64);
        }
        const unsigned short* Ab = A_lds[it & 1];
#pragma unroll
        for (int ks = 0; ks < 2; ks++) {
            short8_t afr[2], bfr[9];
#pragma unroll
            for (int mt = 0; mt < 2; mt++)
                afr[mt] = *(const short8_t*)&Ab[arow[mt] + (((kg + ks * 4) ^ axor) << 3)];
#pragma unroll
            for (int nt = 0; nt < 9; nt++)
                bfr[nt] = *(const short8_t*)(bbase[nt] + it * 64 + ks * 32);
#pragma unroll
            for (int mt = 0; mt < 2; mt++)
#pragma unroll
                for (int nt = 0; nt < 9; nt++)
                    acc[mt][nt] = __builtin_amdgcn_mfma_f32_16x16x32_bf16(afr[mt], bfr[nt], acc[mt][nt], 0, 0, 0);
        }
        __syncthreads();
    }

    float* dst = (kc == 0) ? out0 : (parts + (size_t)(kc - 1) * 2359296);
#pragma unroll
    for (int mt = 0; mt < 2; mt++) {
        int co = m0 * 128 + wid * 32 + mt * 16 + kg * 4;
#pragma unroll
        for (int nt = 0; nt < 9; nt++) {
            int p = nt * 16 + l16;
            *(f32x4*)&dst[((size_t)batch * 144 + p) * 512 + co] = acc[mt][nt];
        }
    }
}

__global__ void reduce_out0(float* __restrict__ out0, const float* __restrict__ parts) {
    size_t i = ((size_t)blockIdx.x * 256 + threadIdx.x) * 4;
    f32x4 a = *(const f32x4*)(out0 + i);
    f32x4 p0 = *(const f32x4*)(parts + i);
    f32x4 p1 = *(const f32x4*)(parts + 2359296 + i);
    f32x4 p2 = *(const f32x4*)(parts + 2 * 2359296 + i);
    a.x += p0.x + p1.x + p2.x;
    a.y += p0.y + p1.y + p2.y;
    a.z += p0.z + p1.z + p2.z;
    a.w += p0.w + p1.w + p2.w;
    *(f32x4*)(out0 + i) = a;
}

// ---------------- topo: wave-per-(c,q) dot, then per-batch MST+sort+lin1 ----------------
__global__ __launch_bounds__(64)
void topo_pts(const float* __restrict__ out0, const float* __restrict__ wt,
              float* __restrict__ pts) {
    int lane = threadIdx.x;
    int cq = blockIdx.x;                 // 0..59
    int b = blockIdx.y;
    int c = cq / 20, q = cq % 20;
    const float* xbase = out0 + ((size_t)b * 144 + 6 * q) * 512 + lane * 8;
    const float* wbase = wt + c * 15360 + lane * 8;
    float s = 0.f;
    for (int r = 0; r < 30; r++) {
        f32x4 a0 = *(const f32x4*)(xbase + r * 512);
        f32x4 a1 = *(const f32x4*)(xbase + r * 512 + 4);
        f32x4 w0 = *(const f32x4*)(wbase + r * 512);
        f32x4 w1 = *(const f32x4*)(wbase + r * 512 + 4);
        s += a0.x * w0.x + a0.y * w0.y + a0.z * w0.z + a0.w * w0.w
           + a1.x * w1.x + a1.y * w1.y + a1.z * w1.z + a1.w * w1.w;
    }
#pragma unroll
    for (int off = 32; off; off >>= 1) s += __shfl_xor(s, off);
    if (lane == 0) pts[b * 60 + q * 3 + c] = s;
}

__global__ __launch_bounds__(192)
void topo_fin(const float* __restrict__ pts, const float* __restrict__ bias,
              const float* __restrict__ lin1w, unsigned short* __restrict__ t1bf) {
    __shared__ float ptsS[60];
    __shared__ float wsS[19];
    __shared__ float pdS[19];
    int tid = threadIdx.x, b = blockIdx.x;
    if (tid < 60) ptsS[tid] = pts[b * 60 + tid] + bias[tid % 3];
    __syncthreads();
    if (tid < 32) {
        int j = tid;
        float px = 0.f, py = 0.f, pz = 0.f;
        if (j < 20) { px = ptsS[j * 3]; py = ptsS[j * 3 + 1]; pz = ptsS[j * 3 + 2]; }
        float dx = px - ptsS[0], dy = py - ptsS[1], dz = pz - ptsS[2];
        float dist = sqrtf(dx * dx + dy * dy + dz * dz + 1e-12f);
        bool intree = (j == 0);
        for (int it = 0; it < 19; it++) {
            float dv = (j < 20 && !intree) ? dist : 1e30f;
            int di = j;
#pragma unroll
            for (int off = 16; off; off >>= 1) {
                float ov = __shfl_xor(dv, off, 32);
                int oi = __shfl_xor(di, off, 32);
                if (ov < dv || (ov == dv && oi < di)) { dv = ov; di = oi; }
            }
            if (j == 0) wsS[it] = dv;
            if (j == di) intree = true;
            float ex = px - ptsS[di * 3], ey = py - ptsS[di * 3 + 1], ez = pz - ptsS[di * 3 + 2];
            float nd = sqrtf(ex * ex + ey * ey + ez * ez + 1e-12f);
            dist = fminf(dist, nd);
        }
    }
    __syncthreads();
    if (tid < 19) {
        float v = wsS[tid];
        int rank = 0;
        for (int t = 0; t < 19; t++) {
            float u = wsS[t];
            rank += (u < v || (u == v && t < tid)) ? 1 : 0;
        }
        pdS[rank] = v;
    }
    __syncthreads();
    if (tid < 160) {
        float s = 0.f;
        if (tid < 144) {
#pragma unroll
            for (int i = 0; i < 19; i++) s += pdS[i] * lin1w[tid * 19 + i];
            s = fmaxf(s, 0.f);
        }
        t1bf[b * 160 + tid] = (tid < 144) ? f2bf(s) : (unsigned short)0;
    }
}

// ---------------- lin2: GEMM M=32 N=73728 K=144(pad 160), f32 weights, relu ----------------
__global__ __launch_bounds__(256)
void lin2_kernel(const unsigned short* __restrict__ t1bf, const float* __restrict__ l2w,
                 float* __restrict__ out1) {
    const int tid = threadIdx.x;
    const int wid = tid >> 6, lane = tid & 63, l16 = lane & 15, kg = lane >> 4;
    const int n0 = blockIdx.x * 256 + wid * 64;
    f32x4 acc[2][4];
#pragma unroll
    for (int i = 0; i < 2; i++)
#pragma unroll
        for (int j = 0; j < 4; j++) acc[i][j] = (f32x4){0.f, 0.f, 0.f, 0.f};

#pragma unroll
    for (int ki = 0; ki < 5; ki++) {
        int kbase = ki * 32 + kg * 8;
        short8_t afr[2], bfr[4];
#pragma unroll
        for (int mt = 0; mt < 2; mt++)
            afr[mt] = *(const short8_t*)(t1bf + (mt * 16 + l16) * 160 + kbase);
#pragma unroll
        for (int nt = 0; nt < 4; nt++) {
            int j = n0 + nt * 16 + l16;
            short8_t v;
            if (kbase < 144) {
                const float* wp = l2w + j * 144 + kbase;
                f32x4 f0 = *(const f32x4*)wp;
                f32x4 f1 = *(const f32x4*)(wp + 4);
                v[0] = (short)f2bf(f0.x); v[1] = (short)f2bf(f0.y);
                v[2] = (short)f2bf(f0.z); v[3] = (short)f2bf(f0.w);
                v[4] = (short)f2bf(f1.x); v[5] = (short)f2bf(f1.y);
                v[6] = (short)f2bf(f1.z); v[7] = (short)f2bf(f1.w);
            } else {
#pragma unroll
                for (int i = 0; i < 8; i++) v[i] = 0;
            }
            bfr[nt] = v;
        }
#pragma unroll
        for (int mt = 0; mt < 2; mt++)
#pragma unroll
            for (int nt = 0; nt < 4; nt++)
                acc[mt][nt] = __builtin_amdgcn_mfma_f32_16x16x32_bf16(afr[mt], bfr[nt], acc[mt][nt], 0, 0, 0);
    }
#pragma unroll
    for (int mt = 0; mt < 2; mt++)
#pragma unroll
        for (int nt = 0; nt < 4; nt++) {
            int jj = n0 + nt * 16 + l16;
#pragma unroll
            for (int i = 0; i < 4; i++) {
                int brow = mt * 16 + kg * 4 + i;
                out1[(size_t)brow * 73728 + jj] = fmaxf(acc[mt][nt][i], 0.f);
            }
        }
}

extern "C" void kernel_launch(void* const* d_in, const int* in_sizes, int n_in,
                              void* d_out, int out_size, void* d_ws, size_t ws_size,
                              hipStream_t stream) {
    const int* x = (const int*)d_in[0];
    const float* embw = (const float*)d_in[1];
    const float* c1w = (const float*)d_in[2];
    const float* c2w = (const float*)d_in[3];
    const float* tw = (const float*)d_in[4];
    const float* tb = (const float*)d_in[5];
    const float* l1w = (const float*)d_in[6];
    const float* l2w = (const float*)d_in[7];
    float* out0 = (float*)d_out;                       // x_seq [32][144][512]
    float* out1 = out0 + (size_t)32 * 144 * 512;       // topo_all_fea

    char* ws = (char*)d_ws;
    unsigned short* wc1  = (unsigned short*)(ws);                  //  2,097,152 B
    unsigned short* wc2  = (unsigned short*)(ws + 2097152);        // 16,515,072 B
    unsigned short* t1   = (unsigned short*)(ws + 18612224);       // 38,518,784 B
    float*          parts= (float*)(ws + 57131008);                // 28,311,552 B (3 x 9.4MB)
    float*          wt   = (float*)(ws + 85442560);                //    184,320 B
    float*          pts  = (float*)(ws + 85626880);                //      7,680 B
    unsigned short* t1bf = (unsigned short*)(ws + 85634560);       //     10,240 B

    prep_wc1<<<dim3(16, 256), 256, 0, stream>>>(c1w, wc1);
    prep_wc2<<<dim3(63, 512), 256, 0, stream>>>(c2w, wc2);
    prep_wt<<<dim3(180), 256, 0, stream>>>(tw, wt);
    conv1_kernel<<<dim3(10, 2, 32), 256, 0, stream>>>(x, embw, wc1, t1);
    conv2_kernel<<<dim3(512), 256, 0, stream>>>(t1, wc2, out0, parts);
    reduce_out0<<<dim3(2304), 256, 0, stream>>>(out0, parts);
    topo_pts<<<dim3(60, 32), 64, 0, stream>>>(out0, wt, pts);
    topo_fin<<<dim3(32), 192, 0, stream>>>(pts, tb, l1w, t1bf);
    lin2_kernel<<<dim3(288), 256, 0, stream>>>(t1bf, l2w, out1);
}

// Round 7
// 501.019 us; speedup vs baseline: 2.6251x; 1.3992x over previous
//
#include <hip/hip_runtime.h>
#include <hip/hip_bf16.h>

typedef __attribute__((ext_vector_type(8))) short short8_t;
typedef __attribute__((ext_vector_type(4))) short short4_t;
typedef __attribute__((ext_vector_type(4))) float f32x4;
typedef unsigned int u32;

#define NTOK 37632
#define L1 2351

__device__ __forceinline__ unsigned short f2bf(float f) {
    union { float f; unsigned u; } v; v.f = f;
    return (unsigned short)((v.u + 0x7FFFu + ((v.u >> 16) & 1u)) >> 16);
}

__device__ __forceinline__ void gload16(void* lds, const void* g) {
    __builtin_amdgcn_global_load_lds((const __attribute__((address_space(1))) u32*)g,
                                     (__attribute__((address_space(3))) u32*)lds, 16, 0, 0);
}

// ---------------- prep kernels: reorder + bf16-cast weights ----------------
__global__ void prep_wc1(const float* __restrict__ w, unsigned short* __restrict__ out) {
    int k = blockIdx.x * 256 + threadIdx.x;   // k = kt*128+ci
    int co = blockIdx.y;
    int kt = k >> 7, ci = k & 127;
    out[co * 4096 + k] = f2bf(w[co * 4096 + ci * 32 + kt]);
}
__global__ void prep_wc2(const float* __restrict__ w, unsigned short* __restrict__ out) {
    int k = blockIdx.x * 256 + threadIdx.x;   // k = kt*256+ci
    int co = blockIdx.y;
    int kt = k >> 8, ci = k & 255;
    out[co * 16128 + k] = f2bf(w[co * 16128 + ci * 63 + kt]);
}
__global__ void prep_wt(const float* __restrict__ w, float* __restrict__ out) {
    int idx = blockIdx.x * 256 + threadIdx.x;  // out[c][r][ci]
    int c = idx / 15360, rem = idx % 15360, r = rem / 512, ci = rem % 512;
    out[idx] = w[c * 15360 + ci * 30 + r];
}

// ---------------- conv1: emb-gather fused GEMM, M=256 N=2351 K=4096 ----------------
__global__ __launch_bounds__(256, 2)
void conv1_kernel(const int* __restrict__ xin, const float* __restrict__ embw,
                  const unsigned short* __restrict__ wc1, unsigned short* __restrict__ t1out) {
    __shared__ unsigned short embS[32768];      // 64 KB
    __shared__ unsigned short A_lds[2][4096];   // 2 x 8 KB (128 rows x 32 k)
    const int tid = threadIdx.x;

#pragma unroll
    for (int c = 0; c < 16; c++) {
        int e0 = c * 2048 + tid * 8;
        int tok = e0 >> 7;
        int slot = (tid & 15) ^ (tok & 15);
        f32x4 f0 = *(const f32x4*)(embw + e0);
        f32x4 f1 = *(const f32x4*)(embw + e0 + 4);
        short8_t v;
        v[0] = (short)f2bf(f0.x); v[1] = (short)f2bf(f0.y);
        v[2] = (short)f2bf(f0.z); v[3] = (short)f2bf(f0.w);
        v[4] = (short)f2bf(f1.x); v[5] = (short)f2bf(f1.y);
        v[6] = (short)f2bf(f1.z); v[7] = (short)f2bf(f1.w);
        *(short8_t*)&embS[tok * 128 + slot * 8] = v;
    }

    const int b = blockIdx.z;
    const int m0 = blockIdx.y;            // co base = m0*128
    const int p0 = blockIdx.x * 256;
    const int wid = tid >> 6, lane = tid & 63;
    const int l16 = lane & 15, kg = lane >> 4;
    const int* xb = xin + b * NTOK;

    int pst[4], pcol[4];
#pragma unroll
    for (int nt = 0; nt < 4; nt++) {
        int p = p0 + wid * 64 + nt * 16 + l16;
        pst[nt] = p; pcol[nt] = (p < L1) ? p : (L1 - 1);
    }

    const int srow0 = tid >> 2;
    const int srow1 = 64 + srow0;
    const unsigned short* asrc0 = wc1 + (m0 * 128 + srow0) * 4096 + (((tid & 3) ^ ((srow0 >> 1) & 3)) << 3);
    const unsigned short* asrc1 = wc1 + (m0 * 128 + srow1) * 4096 + (((tid & 3) ^ ((srow1 >> 1) & 3)) << 3);

    int aidx[8];
#pragma unroll
    for (int mt = 0; mt < 8; mt++) {
        int row = mt * 16 + l16;
        aidx[mt] = row * 32 + ((kg ^ ((row >> 1) & 3)) << 3);
    }

    f32x4 acc[8][4];
#pragma unroll
    for (int i = 0; i < 8; i++)
#pragma unroll
        for (int j = 0; j < 4; j++) acc[i][j] = (f32x4){0.f, 0.f, 0.f, 0.f};

    int tokn[4];
#pragma unroll
    for (int nt = 0; nt < 4; nt++) tokn[nt] = xb[16 * pcol[nt]];

    {
        unsigned short* base = &A_lds[0][wid << 9];
        gload16(base, asrc0);
        gload16(base + 2048, asrc1);
    }
    __syncthreads();

    int tokbase[4], tokxor[4];
    for (int ks = 0; ks < 4096; ks += 32) {
        int it = ks >> 5;
        if (it + 1 < 128) {
            unsigned short* base = &A_lds[(it + 1) & 1][wid << 9];
            gload16(base, asrc0 + ks + 32);
            gload16(base + 2048, asrc1 + ks + 32);
        }
        if ((ks & 127) == 0) {
#pragma unroll
            for (int nt = 0; nt < 4; nt++) { int tk = tokn[nt]; tokbase[nt] = tk << 7; tokxor[nt] = tk & 15; }
            int tnext = (ks >> 7) + 1;
            if (tnext < 32) {
#pragma unroll
                for (int nt = 0; nt < 4; nt++) tokn[nt] = xb[16 * pcol[nt] + tnext];
            }
        }
        const unsigned short* Ab = A_lds[it & 1];
        int s0 = (ks >> 3) & 15;
        short8_t bfr[4], afr[8];
#pragma unroll
        for (int nt = 0; nt < 4; nt++)
            bfr[nt] = *(const short8_t*)&embS[tokbase[nt] + (((s0 + kg) ^ tokxor[nt]) << 3)];
#pragma unroll
        for (int mt = 0; mt < 8; mt++)
            afr[mt] = *(const short8_t*)&Ab[aidx[mt]];
#pragma unroll
        for (int mt = 0; mt < 8; mt++)
#pragma unroll
            for (int nt = 0; nt < 4; nt++)
                acc[mt][nt] = __builtin_amdgcn_mfma_f32_16x16x32_bf16(afr[mt], bfr[nt], acc[mt][nt], 0, 0, 0);
        __syncthreads();
    }

#pragma unroll
    for (int mt = 0; mt < 8; mt++) {
        int co = m0 * 128 + mt * 16 + kg * 4;
#pragma unroll
        for (int nt = 0; nt < 4; nt++) {
            int p = pst[nt];
            if (p >= L1) continue;
            short4_t pk;
            pk.x = (short)f2bf(acc[mt][nt].x);
            pk.y = (short)f2bf(acc[mt][nt].y);
            pk.z = (short)f2bf(acc[mt][nt].z);
            pk.w = (short)f2bf(acc[mt][nt].w);
            *(short4_t*)&t1out[((size_t)b * L1 + p) * 256 + co] = pk;
        }
    }
}

// ---------------- conv2: GEMM M=512 N=32x144 K=16128 ----------------
// Block: BM=128 x BN=144 (one batch), BK=64, K-split x4 via partial buffers.
// Batch-pinned XCDs: batch = bid&31 -> XCD = bid%8 = batch%8; all 16 (m0,kc)
// blocks of a batch co-XCD -> B (t1) slice 1.2MB L2-resident, m0/kc re-reads hit L2.
// Both A and B staged via global_load_lds (coalesced), XOR-swizzled, double-buffered.
__global__ __launch_bounds__(256, 2)
void conv2_kernel(const unsigned short* __restrict__ t1, const unsigned short* __restrict__ wc2,
                  float* __restrict__ out0, float* __restrict__ parts) {
    __shared__ unsigned short A_lds[2][8192];   // 2 x 16 KB: [128 rows][64 k]
    __shared__ unsigned short B_lds[2][9216];   // 2 x 18 KB: [144 windows][64 k]
    const int tid = threadIdx.x;
    const int bid = blockIdx.x;
    const int batch = bid & 31, combo = bid >> 5;
    const int m0 = combo & 3, kc = combo >> 2;
    const int k0 = kc * 4032;
    const int wid = tid >> 6, lane = tid & 63, l16 = lane & 15, kg = lane >> 4;
    const unsigned short* t1b = t1 + (size_t)batch * (L1 * 256);

    // A staging: thread -> row r = i*32 + (tid>>3), chunk tid&7; inverse-swizzled src
    const int srow = tid >> 3, schunk = tid & 7;
    const unsigned short* asrc[4];
#pragma unroll
    for (int i = 0; i < 4; i++) {
        int r = i * 32 + srow;
        asrc[i] = wc2 + (size_t)(m0 * 128 + r) * 16128 + k0 + ((schunk ^ (r & 7)) << 3);
    }

    // B staging: 5 rounds; wave covers 8 consecutive windows per round.
    // round r: window w = r*32 + wid*8 + (lane>>3); lane chunk = lane&7 (16B);
    // src chunk inverse-swizzled by w&7 (= swin&7, since r*32 % 8 == 0).
    const int swin = wid * 8 + (lane >> 3);     // 0..31
    const int sxorB = (((lane & 7) ^ (swin & 7)) << 3);
    const unsigned short* bsrc[5];
#pragma unroll
    for (int r = 0; r < 5; r++) {
        int w = r * 32 + swin;
        if (w > 143) w = 143;                   // round 4 handled only by wid<2; clamp keeps ptr valid
        bsrc[r] = t1b + (size_t)w * 4096 + k0 + sxorB;
    }

    // ds_read: A row = wid*32 + mt*16 + l16; B window = nt*16 + l16;
    // phys chunk = (kg + ks*4) ^ (l16 & 7)  (involution with staging swizzle)
    int arow[2];
#pragma unroll
    for (int mt = 0; mt < 2; mt++) arow[mt] = (wid * 32 + mt * 16 + l16) * 64;
    const int axor = l16 & 7;

    f32x4 acc[2][9];
#pragma unroll
    for (int i = 0; i < 2; i++)
#pragma unroll
        for (int j = 0; j < 9; j++) acc[i][j] = (f32x4){0.f, 0.f, 0.f, 0.f};

    {   // prologue: stage it=0 into buf0
        unsigned short* baseA = &A_lds[0][wid << 9];
#pragma unroll
        for (int i = 0; i < 4; i++) gload16(baseA + i * 2048, asrc[i]);
#pragma unroll
        for (int r = 0; r < 4; r++) gload16(&B_lds[0][(r * 32 + wid * 8) * 64], bsrc[r]);
        if (wid < 2) gload16(&B_lds[0][(128 + wid * 8) * 64], bsrc[4]);
    }
    __syncthreads();

    for (int it = 0; it < 63; it++) {
        if (it + 1 < 63) {
            int nb = (it + 1) & 1;
            int off = (it + 1) * 64;
            unsigned short* baseA = &A_lds[nb][wid << 9];
#pragma unroll
            for (int i = 0; i < 4; i++) gload16(baseA + i * 2048, asrc[i] + off);
#pragma unroll
            for (int r = 0; r < 4; r++) gload16(&B_lds[nb][(r * 32 + wid * 8) * 64], bsrc[r] + off);
            if (wid < 2) gload16(&B_lds[nb][(128 + wid * 8) * 64], bsrc[4] + off);
        }
        const unsigned short* Ab = A_lds[it & 1];
        const unsigned short* Bb = B_lds[it & 1];
#pragma unroll
        for (int ks = 0; ks < 2; ks++) {
            short8_t afr[2], bfr[9];
#pragma unroll
            for (int mt = 0; mt < 2; mt++)
                afr[mt] = *(const short8_t*)&Ab[arow[mt] + (((kg + ks * 4) ^ axor) << 3)];
#pragma unroll
            for (int nt = 0; nt < 9; nt++)
                bfr[nt] = *(const short8_t*)&Bb[(nt * 16 + l16) * 64 + (((kg + ks * 4) ^ axor) << 3)];
#pragma unroll
            for (int mt = 0; mt < 2; mt++)
#pragma unroll
                for (int nt = 0; nt < 9; nt++)
                    acc[mt][nt] = __builtin_amdgcn_mfma_f32_16x16x32_bf16(afr[mt], bfr[nt], acc[mt][nt], 0, 0, 0);
        }
        __syncthreads();
    }

    float* dst = (kc == 0) ? out0 : (parts + (size_t)(kc - 1) * 2359296);
#pragma unroll
    for (int mt = 0; mt < 2; mt++) {
        int co = m0 * 128 + wid * 32 + mt * 16 + kg * 4;
#pragma unroll
        for (int nt = 0; nt < 9; nt++) {
            int p = nt * 16 + l16;
            *(f32x4*)&dst[((size_t)batch * 144 + p) * 512 + co] = acc[mt][nt];
        }
    }
}

__global__ void reduce_out0(float* __restrict__ out0, const float* __restrict__ parts) {
    size_t i = ((size_t)blockIdx.x * 256 + threadIdx.x) * 4;
    f32x4 a = *(const f32x4*)(out0 + i);
    f32x4 p0 = *(const f32x4*)(parts + i);
    f32x4 p1 = *(const f32x4*)(parts + 2359296 + i);
    f32x4 p2 = *(const f32x4*)(parts + 2 * 2359296 + i);
    a.x += p0.x + p1.x + p2.x;
    a.y += p0.y + p1.y + p2.y;
    a.z += p0.z + p1.z + p2.z;
    a.w += p0.w + p1.w + p2.w;
    *(f32x4*)(out0 + i) = a;
}

// ---------------- topo: wave-per-(c,q) dot, then per-batch MST+sort+lin1 ----------------
__global__ __launch_bounds__(64)
void topo_pts(const float* __restrict__ out0, const float* __restrict__ wt,
              float* __restrict__ pts) {
    int lane = threadIdx.x;
    int cq = blockIdx.x;                 // 0..59
    int b = blockIdx.y;
    int c = cq / 20, q = cq % 20;
    const float* xbase = out0 + ((size_t)b * 144 + 6 * q) * 512 + lane * 8;
    const float* wbase = wt + c * 15360 + lane * 8;
    float s = 0.f;
    for (int r = 0; r < 30; r++) {
        f32x4 a0 = *(const f32x4*)(xbase + r * 512);
        f32x4 a1 = *(const f32x4*)(xbase + r * 512 + 4);
        f32x4 w0 = *(const f32x4*)(wbase + r * 512);
        f32x4 w1 = *(const f32x4*)(wbase + r * 512 + 4);
        s += a0.x * w0.x + a0.y * w0.y + a0.z * w0.z + a0.w * w0.w
           + a1.x * w1.x + a1.y * w1.y + a1.z * w1.z + a1.w * w1.w;
    }
#pragma unroll
    for (int off = 32; off; off >>= 1) s += __shfl_xor(s, off);
    if (lane == 0) pts[b * 60 + q * 3 + c] = s;
}

__global__ __launch_bounds__(192)
void topo_fin(const float* __restrict__ pts, const float* __restrict__ bias,
              const float* __restrict__ lin1w, unsigned short* __restrict__ t1bf) {
    __shared__ float ptsS[60];
    __shared__ float wsS[19];
    __shared__ float pdS[19];
    int tid = threadIdx.x, b = blockIdx.x;
    if (tid < 60) ptsS[tid] = pts[b * 60 + tid] + bias[tid % 3];
    __syncthreads();
    if (tid < 32) {
        int j = tid;
        float px = 0.f, py = 0.f, pz = 0.f;
        if (j < 20) { px = ptsS[j * 3]; py = ptsS[j * 3 + 1]; pz = ptsS[j * 3 + 2]; }
        float dx = px - ptsS[0], dy = py - ptsS[1], dz = pz - ptsS[2];
        float dist = sqrtf(dx * dx + dy * dy + dz * dz + 1e-12f);
        bool intree = (j == 0);
        for (int it = 0; it < 19; it++) {
            float dv = (j < 20 && !intree) ? dist : 1e30f;
            int di = j;
#pragma unroll
            for (int off = 16; off; off >>= 1) {
                float ov = __shfl_xor(dv, off, 32);
                int oi = __shfl_xor(di, off, 32);
                if (ov < dv || (ov == dv && oi < di)) { dv = ov; di = oi; }
            }
            if (j == 0) wsS[it] = dv;
            if (j == di) intree = true;
            float ex = px - ptsS[di * 3], ey = py - ptsS[di * 3 + 1], ez = pz - ptsS[di * 3 + 2];
            float nd = sqrtf(ex * ex + ey * ey + ez * ez + 1e-12f);
            dist = fminf(dist, nd);
        }
    }
    __syncthreads();
    if (tid < 19) {
        float v = wsS[tid];
        int rank = 0;
        for (int t = 0; t < 19; t++) {
            float u = wsS[t];
            rank += (u < v || (u == v && t < tid)) ? 1 : 0;
        }
        pdS[rank] = v;
    }
    __syncthreads();
    if (tid < 160) {
        float s = 0.f;
        if (tid < 144) {
#pragma unroll
            for (int i = 0; i < 19; i++) s += pdS[i] * lin1w[tid * 19 + i];
            s = fmaxf(s, 0.f);
        }
        t1bf[b * 160 + tid] = (tid < 144) ? f2bf(s) : (unsigned short)0;
    }
}

// ---------------- lin2: GEMM M=32 N=73728 K=144(pad 160), f32 weights, relu ----------------
__global__ __launch_bounds__(256)
void lin2_kernel(const unsigned short* __restrict__ t1bf, const float* __restrict__ l2w,
                 float* __restrict__ out1) {
    const int tid = threadIdx.x;
    const int wid = tid >> 6, lane = tid & 63, l16 = lane & 15, kg = lane >> 4;
    const int n0 = blockIdx.x * 256 + wid * 64;
    f32x4 acc[2][4];
#pragma unroll
    for (int i = 0; i < 2; i++)
#pragma unroll
        for (int j = 0; j < 4; j++) acc[i][j] = (f32x4){0.f, 0.f, 0.f, 0.f};

#pragma unroll
    for (int ki = 0; ki < 5; ki++) {
        int kbase = ki * 32 + kg * 8;
        short8_t afr[2], bfr[4];
#pragma unroll
        for (int mt = 0; mt < 2; mt++)
            afr[mt] = *(const short8_t*)(t1bf + (mt * 16 + l16) * 160 + kbase);
#pragma unroll
        for (int nt = 0; nt < 4; nt++) {
            int j = n0 + nt * 16 + l16;
            short8_t v;
            if (kbase < 144) {
                const float* wp = l2w + j * 144 + kbase;
                f32x4 f0 = *(const f32x4*)wp;
                f32x4 f1 = *(const f32x4*)(wp + 4);
                v[0] = (short)f2bf(f0.x); v[1] = (short)f2bf(f0.y);
                v[2] = (short)f2bf(f0.z); v[3] = (short)f2bf(f0.w);
                v[4] = (short)f2bf(f1.x); v[5] = (short)f2bf(f1.y);
                v[6] = (short)f2bf(f1.z); v[7] = (short)f2bf(f1.w);
            } else {
#pragma unroll
                for (int i = 0; i < 8; i++) v[i] = 0;
            }
            bfr[nt] = v;
        }
#pragma unroll
        for (int mt = 0; mt < 2; mt++)
#pragma unroll
            for (int nt = 0; nt < 4; nt++)
                acc[mt][nt] = __builtin_amdgcn_mfma_f32_16x16x32_bf16(afr[mt], bfr[nt], acc[mt][nt], 0, 0, 0);
    }
#pragma unroll
    for (int mt = 0; mt < 2; mt++)
#pragma unroll
        for (int nt = 0; nt < 4; nt++) {
            int jj = n0 + nt * 16 + l16;
#pragma unroll
            for (int i = 0; i < 4; i++) {
                int brow = mt * 16 + kg * 4 + i;
                out1[(size_t)brow * 73728 + jj] = fmaxf(acc[mt][nt][i], 0.f);
            }
        }
}

extern "C" void kernel_launch(void* const* d_in, const int* in_sizes, int n_in,
                              void* d_out, int out_size, void* d_ws, size_t ws_size,
                              hipStream_t stream) {
    const int* x = (const int*)d_in[0];
    const float* embw = (const float*)d_in[1];
    const float* c1w = (const float*)d_in[2];
    const float* c2w = (const float*)d_in[3];
    const float* tw = (const float*)d_in[4];
    const float* tb = (const float*)d_in[5];
    const float* l1w = (const float*)d_in[6];
    const float* l2w = (const float*)d_in[7];
    float* out0 = (float*)d_out;                       // x_seq [32][144][512]
    float* out1 = out0 + (size_t)32 * 144 * 512;       // topo_all_fea

    char* ws = (char*)d_ws;
    unsigned short* wc1  = (unsigned short*)(ws);                  //  2,097,152 B
    unsigned short* wc2  = (unsigned short*)(ws + 2097152);        // 16,515,072 B
    unsigned short* t1   = (unsigned short*)(ws + 18612224);       // 38,518,784 B
    float*          parts= (float*)(ws + 57131008);                // 28,311,552 B (3 x 9.4MB)
    float*          wt   = (float*)(ws + 85442560);                //    184,320 B
    float*          pts  = (float*)(ws + 85626880);                //      7,680 B
    unsigned short* t1bf = (unsigned short*)(ws + 85634560);       //     10,240 B

    prep_wc1<<<dim3(16, 256), 256, 0, stream>>>(c1w, wc1);
    prep_wc2<<<dim3(63, 512), 256, 0, stream>>>(c2w, wc2);
    prep_wt<<<dim3(180), 256, 0, stream>>>(tw, wt);
    conv1_kernel<<<dim3(10, 2, 32), 256, 0, stream>>>(x, embw, wc1, t1);
    conv2_kernel<<<dim3(512), 256, 0, stream>>>(t1, wc2, out0, parts);
    reduce_out0<<<dim3(2304), 256, 0, stream>>>(out0, parts);
    topo_pts<<<dim3(60, 32), 64, 0, stream>>>(out0, wt, pts);
    topo_fin<<<dim3(32), 192, 0, stream>>>(pts, tb, l1w, t1bf);
    lin2_kernel<<<dim3(288), 256, 0, stream>>>(t1bf, l2w, out1);
}